// Round 8
// baseline (844.028 us; speedup 1.0000x reference)
//
#include <hip/hip_runtime.h>
#include <hip/hip_bf16.h>

typedef __attribute__((ext_vector_type(8))) __bf16 bf16x8;
typedef __attribute__((ext_vector_type(4))) __bf16 bf16x4;
typedef __attribute__((ext_vector_type(4))) float f32x4;

#define MFMA16(a, b, c) __builtin_amdgcn_mfma_f32_16x16x32_bf16((a), (b), (c), 0, 0, 0)

// B=2, S=2048, D=1024, H=16, DK=64
#define SEQ 2048
#define DIM 1024

// Async global->LDS, 16B per lane. LDS dest must be WAVE-UNIFORM base
// (HW adds lane*16); global src is per-lane. LDS layout must be linear.
__device__ __forceinline__ void gload_lds16(const __bf16* g, __bf16* l) {
  __builtin_amdgcn_global_load_lds(
      (const __attribute__((address_space(1))) void*)g,
      (__attribute__((address_space(3))) void*)l, 16, 0, 0);
}

// ---------------------------------------------------------------------------
// One-shot fp32 -> bf16 convert of the 3 inputs and 4 weight matrices.
// ---------------------------------------------------------------------------
__global__ __launch_bounds__(256) void cvt_bf16(
    const float* __restrict__ q, const float* __restrict__ k, const float* __restrict__ v,
    const float* __restrict__ wq, const float* __restrict__ wk, const float* __restrict__ wv,
    const float* __restrict__ wo,
    __bf16* __restrict__ qb, __bf16* __restrict__ kb, __bf16* __restrict__ vb,
    __bf16* __restrict__ wqb, __bf16* __restrict__ wkb, __bf16* __restrict__ wvb,
    __bf16* __restrict__ wob) {
  int a = blockIdx.y;
  const float* src = (a == 0) ? q : (a == 1) ? k : (a == 2) ? v
                    : (a == 3) ? wq : (a == 4) ? wk : (a == 5) ? wv : wo;
  __bf16* dst = (a == 0) ? qb : (a == 1) ? kb : (a == 2) ? vb
               : (a == 3) ? wqb : (a == 4) ? wkb : (a == 5) ? wvb : wob;
  size_t n = (a < 3) ? (size_t)(2 * SEQ * DIM) : (size_t)(DIM * DIM);
  size_t i = ((size_t)blockIdx.x * 256 + threadIdx.x) * 8;
  if (i >= n) return;
  float4 f0 = *(const float4*)&src[i];
  float4 f1 = *(const float4*)&src[i + 4];
  bf16x8 o = {(__bf16)f0.x, (__bf16)f0.y, (__bf16)f0.z, (__bf16)f0.w,
              (__bf16)f1.x, (__bf16)f1.y, (__bf16)f1.z, (__bf16)f1.w};
  *(bf16x8*)&dst[i] = o;
}

// ---------------------------------------------------------------------------
// QKV projection, m97-style (FROZEN — at the m102 shape-curve ceiling for
// this geometry, ~323 TF).
// ---------------------------------------------------------------------------
__global__ __launch_bounds__(256) void qkv_gemm(
    const __bf16* __restrict__ qI, const __bf16* __restrict__ kI, const __bf16* __restrict__ vI,
    const __bf16* __restrict__ wqI, const __bf16* __restrict__ wkI, const __bf16* __restrict__ wvI,
    const float* __restrict__ bqI, const float* __restrict__ bkI, const float* __restrict__ bvI,
    __bf16* __restrict__ Qp, __bf16* __restrict__ Kp, __bf16* __restrict__ Vt) {
  const int N = 1024, K = 1024;
  int z = blockIdx.z;
  const __bf16* A = (z == 0) ? qI : (z == 1) ? kI : vI;
  const __bf16* W = (z == 0) ? wqI : (z == 1) ? wkI : wvI;
  const float* bias = (z == 0) ? bqI : (z == 1) ? bkI : bvI;

  __shared__ __bf16 As[2][128 * 32];
  __shared__ __bf16 Bs[2][128 * 32];

  int tid = threadIdx.x;
  int wave = tid >> 6, lane = tid & 63;
  int quad = lane >> 4, l16 = lane & 15;
  int wm = (wave >> 1) * 64, wn = (wave & 1) * 64;
  int m0 = blockIdx.y * 128, n0 = blockIdx.x * 128;

  int srow = wave * 16 + (lane >> 2);
  int scol = (lane & 3) * 8;
  const __bf16* Ab = &A[(size_t)(m0 + srow) * K + scol];
  const __bf16* Wb = &W[(size_t)(n0 + srow) * K + scol];
  int lo = wave * 512;

  f32x4 acc[4][4] = {};

  {
    gload_lds16(Ab, &As[0][lo]);
    gload_lds16(Ab + (size_t)64 * K, &As[0][lo + 2048]);
    gload_lds16(Wb, &Bs[0][lo]);
    gload_lds16(Wb + (size_t)64 * K, &Bs[0][lo + 2048]);
  }

  int buf = 0;
  for (int k0 = 0; k0 < K; k0 += 32) {
    __syncthreads();
    if (k0 + 32 < K) {
      int nb = buf ^ 1;
      gload_lds16(Ab + k0 + 32, &As[nb][lo]);
      gload_lds16(Ab + (size_t)64 * K + k0 + 32, &As[nb][lo + 2048]);
      gload_lds16(Wb + k0 + 32, &Bs[nb][lo]);
      gload_lds16(Wb + (size_t)64 * K + k0 + 32, &Bs[nb][lo + 2048]);
    }
    const __bf16* as = &As[buf][0];
    const __bf16* bs = &Bs[buf][0];
    bf16x8 af[4], bfv[4];
#pragma unroll
    for (int i = 0; i < 4; i++) af[i] = *(const bf16x8*)&as[(wm + i * 16 + l16) * 32 + quad * 8];
#pragma unroll
    for (int j = 0; j < 4; j++) bfv[j] = *(const bf16x8*)&bs[(wn + j * 16 + l16) * 32 + quad * 8];
#pragma unroll
    for (int i = 0; i < 4; i++)
#pragma unroll
      for (int j = 0; j < 4; j++) acc[i][j] = MFMA16(af[i], bfv[j], acc[i][j]);
    buf ^= 1;
  }

#pragma unroll
  for (int j = 0; j < 4; j++) {
    int col = n0 + wn + j * 16 + l16;
    float bj = bias[col];
    if (z == 2) {
#pragma unroll
      for (int i = 0; i < 4; i++) {
        int row0 = m0 + wm + i * 16 + quad * 4;
        int bb = row0 >> 11, s = row0 & 2047;
        bf16x4 pv = {(__bf16)(acc[i][j][0] + bj), (__bf16)(acc[i][j][1] + bj),
                     (__bf16)(acc[i][j][2] + bj), (__bf16)(acc[i][j][3] + bj)};
        *(bf16x4*)&Vt[((size_t)bb * 1024 + col) * SEQ + s] = pv;
      }
    } else {
      __bf16* C = (z == 0) ? Qp : Kp;
      float scale = (z == 0) ? 0.125f : 1.0f;
#pragma unroll
      for (int i = 0; i < 4; i++)
#pragma unroll
        for (int r = 0; r < 4; r++) {
          int row = m0 + wm + i * 16 + quad * 4 + r;
          C[(size_t)row * N + col] = (__bf16)((acc[i][j][r] + bj) * scale);
        }
    }
  }
}

// ---------------------------------------------------------------------------
// Output projection (FROZEN).
// ---------------------------------------------------------------------------
__global__ __launch_bounds__(256) void out_gemm(
    const __bf16* __restrict__ A, const __bf16* __restrict__ W,
    const float* __restrict__ bias, float* __restrict__ C) {
  const int N = 1024, K = 1024;
  __shared__ __bf16 As[2][128 * 32];
  __shared__ __bf16 Bs[2][128 * 32];

  int tid = threadIdx.x;
  int wave = tid >> 6, lane = tid & 63;
  int quad = lane >> 4, l16 = lane & 15;
  int wm = (wave >> 1) * 64, wn = (wave & 1) * 64;
  int m0 = blockIdx.y * 128, n0 = blockIdx.x * 128;

  int srow = wave * 16 + (lane >> 2);
  int scol = (lane & 3) * 8;
  const __bf16* Ab = &A[(size_t)(m0 + srow) * K + scol];
  const __bf16* Wb = &W[(size_t)(n0 + srow) * K + scol];
  int lo = wave * 512;

  f32x4 acc[4][4] = {};

  {
    gload_lds16(Ab, &As[0][lo]);
    gload_lds16(Ab + (size_t)64 * K, &As[0][lo + 2048]);
    gload_lds16(Wb, &Bs[0][lo]);
    gload_lds16(Wb + (size_t)64 * K, &Bs[0][lo + 2048]);
  }

  int buf = 0;
  for (int k0 = 0; k0 < K; k0 += 32) {
    __syncthreads();
    if (k0 + 32 < K) {
      int nb = buf ^ 1;
      gload_lds16(Ab + k0 + 32, &As[nb][lo]);
      gload_lds16(Ab + (size_t)64 * K + k0 + 32, &As[nb][lo + 2048]);
      gload_lds16(Wb + k0 + 32, &Bs[nb][lo]);
      gload_lds16(Wb + (size_t)64 * K + k0 + 32, &Bs[nb][lo + 2048]);
    }
    const __bf16* as = &As[buf][0];
    const __bf16* bs = &Bs[buf][0];
    bf16x8 af[4], bfv[4];
#pragma unroll
    for (int i = 0; i < 4; i++) af[i] = *(const bf16x8*)&as[(wm + i * 16 + l16) * 32 + quad * 8];
#pragma unroll
    for (int j = 0; j < 4; j++) bfv[j] = *(const bf16x8*)&bs[(wn + j * 16 + l16) * 32 + quad * 8];
#pragma unroll
    for (int i = 0; i < 4; i++)
#pragma unroll
      for (int j = 0; j < 4; j++) acc[i][j] = MFMA16(af[i], bfv[j], acc[i][j]);
    buf ^= 1;
  }

#pragma unroll
  for (int j = 0; j < 4; j++) {
    int col = n0 + wn + j * 16 + l16;
    float bj = bias[col];
#pragma unroll
    for (int i = 0; i < 4; i++)
#pragma unroll
      for (int r = 0; r < 4; r++) {
        int row = m0 + wm + i * 16 + quad * 4 + r;
        C[(size_t)row * N + col] = acc[i][j][r] + bj;
      }
  }
}

// ---------------------------------------------------------------------------
// Fused causal attention — R4 structure with EXACTLY ONE change: XOR-swizzled
// LDS tiles (T2 / G4). The static bank math for the old padded layouts
// ([72]/[136] strides) gives an 8-WAY conflict on every ds_read_b128
// (bank start = 4*(l16+quad) mod 32 -> 8 lanes per 4-bank group): ~36 b128
// reads/wave/tile at ~2.94x cost ≈ 1270 cy vs only ~160 cy of MFMA — the
// LDS reads are the per-tile critical path (explains R5/R6 null/regress).
// Fix: LINEAR rows (no pad), 16B-slot index XOR'd with row:
//   Ks  [128][64]: slot' = slot ^ (row&7)   (8 slots/row)
//   Vts [64][128]: slot' = slot ^ (row&15)  (16 slots/row)
//   Ps  [64][128]: slot' = slot ^ (row&15)
// Write and read sides apply the SAME mapping (both-sides-or-neither).
// Result: reads become 2-way (free, m136). LDS 53 -> 48 KB.
// C-layout of S^T = K.Q^T per lane (quad,l16): q=l16, k=t*16+quad*4+r.
// ---------------------------------------------------------------------------
__global__ __launch_bounds__(256) void attn_fused(
    const __bf16* __restrict__ Qp, const __bf16* __restrict__ Kp,
    const __bf16* __restrict__ Vt, float* __restrict__ attn,
    __bf16* __restrict__ Oc) {
  int bh = blockIdx.y;
  int b = bh >> 4;
  int hofs = (bh & 15) * 64;
  int q0 = blockIdx.x * 64;

  int tid = threadIdx.x;
  int wave = tid >> 6, lane = tid & 63;
  int quad = lane >> 4, l16 = lane & 15;

  __shared__ __align__(16) __bf16 Ks[128 * 64];    // swizzled, 16 KB
  __shared__ __align__(16) __bf16 Vts[64 * 128];   // swizzled, 16 KB
  __shared__ __align__(16) __bf16 Ps[64 * 128];    // swizzled, 16 KB

  const size_t rowbase = (size_t)b * SEQ;
  const size_t vtbase = (size_t)bh * 64 * SEQ;

  int qg = q0 + wave * 16 + l16;   // this lane's q row

  // loop-invariant Q B-fragments straight from global (read once)
  const __bf16* qpp = &Qp[(rowbase + qg) * DIM + hofs + quad * 8];
  bf16x8 qfrag0 = *(const bf16x8*)qpp;
  bf16x8 qfrag1 = *(const bf16x8*)(qpp + 32);

  float m_i = -1e30f, l_i = 0.f;
  int ktmax = (q0 + 63) >> 7;

  // ---------------- pass 1: row stats ----------------
  for (int kt = 0; kt <= ktmax; kt++) {
    int k0 = kt << 7;
    __syncthreads();
#pragma unroll
    for (int it = 0; it < 4; it++) {
      int flat = tid * 8 + it * 2048;
      int r = flat >> 6, c = flat & 63;            // c = 8*cg, slot-aligned
      int cs = (((c >> 3) ^ (r & 7)) << 3);
      *(bf16x8*)&Ks[r * 64 + cs] = *(const bf16x8*)&Kp[(rowbase + k0 + r) * DIM + hofs + c];
    }
    __syncthreads();

    f32x4 sacc[8] = {};
#pragma unroll
    for (int t = 0; t < 8; t++) {
      int row = t * 16 + l16, rx = row & 7;
      bf16x8 a0 = *(bf16x8*)&Ks[row * 64 + ((quad ^ rx) << 3)];
      bf16x8 a1 = *(bf16x8*)&Ks[row * 64 + (((4 + quad) ^ rx) << 3)];
      sacc[t] = MFMA16(a0, qfrag0, sacc[t]);
      sacc[t] = MFMA16(a1, qfrag1, sacc[t]);
    }

    bool diag = (kt == ktmax);
    float sv[32];
    float mx = -1e30f;
#pragma unroll
    for (int t = 0; t < 8; t++)
#pragma unroll
      for (int r = 0; r < 4; r++) {
        float s = sacc[t][r];
        int k = k0 + t * 16 + quad * 4 + r;
        if (diag && k > qg) s = -1e30f;
        sv[t * 4 + r] = s;
        mx = fmaxf(mx, s);
      }
    mx = fmaxf(mx, __shfl_xor(mx, 16));
    mx = fmaxf(mx, __shfl_xor(mx, 32));
    float mn = fmaxf(m_i, mx);
    float sum = 0.f;
#pragma unroll
    for (int i = 0; i < 32; i++) sum += __expf(sv[i] - mn);
    sum += __shfl_xor(sum, 16);
    sum += __shfl_xor(sum, 32);
    l_i = l_i * __expf(m_i - mn) + sum;
    m_i = mn;
  }

  float rl = 1.f / l_i;
  f32x4 oacc[4] = {};
  float* attn_bh = attn + (size_t)bh * SEQ * SEQ;
  float* attn_row = attn_bh + (size_t)qg * SEQ;

  // ---------------- pass 2: P write + O accumulate ----------------
  for (int kt = 0; kt < SEQ / 128; kt++) {
    int k0 = kt << 7;
    if (kt <= ktmax) {
      __syncthreads();
#pragma unroll
      for (int it = 0; it < 4; it++) {
        int flat = tid * 8 + it * 2048;
        int r = flat >> 6, c = flat & 63;
        int cs = (((c >> 3) ^ (r & 7)) << 3);
        *(bf16x8*)&Ks[r * 64 + cs] = *(const bf16x8*)&Kp[(rowbase + k0 + r) * DIM + hofs + c];
        int d = flat >> 7, c2 = flat & 127;
        int c2s = (((c2 >> 3) ^ (d & 15)) << 3);
        *(bf16x8*)&Vts[d * 128 + c2s] = *(const bf16x8*)&Vt[vtbase + (size_t)d * SEQ + k0 + c2];
      }
      __syncthreads();

      f32x4 sacc[8] = {};
#pragma unroll
      for (int t = 0; t < 8; t++) {
        int row = t * 16 + l16, rx = row & 7;
        bf16x8 a0 = *(bf16x8*)&Ks[row * 64 + ((quad ^ rx) << 3)];
        bf16x8 a1 = *(bf16x8*)&Ks[row * 64 + (((4 + quad) ^ rx) << 3)];
        sacc[t] = MFMA16(a0, qfrag0, sacc[t]);
        sacc[t] = MFMA16(a1, qfrag1, sacc[t]);
      }

      bool diag = (kt == ktmax);
#pragma unroll
      for (int t = 0; t < 8; t++) {
        float p[4];
#pragma unroll
        for (int r = 0; r < 4; r++) {
          int k = k0 + t * 16 + quad * 4 + r;
          float s = sacc[t][r];
          p[r] = (!diag || k <= qg) ? __expf(s - m_i) * rl : 0.f;
        }
        *(float4*)&attn_row[k0 + t * 16 + quad * 4] = make_float4(p[0], p[1], p[2], p[3]);
        bf16x4 ph = {(__bf16)p[0], (__bf16)p[1], (__bf16)p[2], (__bf16)p[3]};
        // col = t*16+quad*4 -> slot = t*2+(quad>>1), in-slot elem = (quad&1)*4
        int ps_col = (((t * 2 + (quad >> 1)) ^ l16) << 3) + ((quad & 1) * 4);
        *(bf16x4*)&Ps[(wave * 16 + l16) * 128 + ps_col] = ph;
      }
      __syncthreads();   // Ps cross-lane visibility (R4-proven sync)

#pragma unroll
      for (int ks = 0; ks < 4; ks++) {
        bf16x8 a = *(bf16x8*)&Ps[(wave * 16 + l16) * 128 + (((ks * 4 + quad) ^ l16) << 3)];
#pragma unroll
        for (int dt = 0; dt < 4; dt++) {
          int vrow = dt * 16 + l16;   // vrow & 15 == l16
          bf16x8 bb = *(bf16x8*)&Vts[vrow * 128 + (((ks * 4 + quad) ^ l16) << 3)];
          oacc[dt] = MFMA16(a, bb, oacc[dt]);
        }
      }
    } else {
      // fully-masked tile: write exact zeros
      float4 z4 = make_float4(0.f, 0.f, 0.f, 0.f);
#pragma unroll
      for (int i = 0; i < 8; i++) {
        int f4 = tid + i * 256;
        int r = f4 >> 5;
        int c = (f4 & 31) * 4;
        *(float4*)&attn_bh[(size_t)(q0 + r) * SEQ + k0 + c] = z4;
      }
    }
  }

  // write O strip (bf16): C-layout col=l16=dk, row=quad*4+rr=q-within-wave
#pragma unroll
  for (int dt = 0; dt < 4; dt++)
#pragma unroll
    for (int rr = 0; rr < 4; rr++) {
      int row = q0 + wave * 16 + quad * 4 + rr;
      Oc[(rowbase + row) * DIM + hofs + dt * 16 + l16] = (__bf16)oacc[dt][rr];
    }
}

// ---------------------------------------------------------------------------
extern "C" void kernel_launch(void* const* d_in, const int* in_sizes, int n_in,
                              void* d_out, int out_size, void* d_ws, size_t ws_size,
                              hipStream_t stream) {
  const float* q = (const float*)d_in[0];
  const float* k = (const float*)d_in[1];
  const float* v = (const float*)d_in[2];
  // d_in[3] = causal mask (tril) — analytic in attn_fused
  const float* wq = (const float*)d_in[4];
  const float* bq = (const float*)d_in[5];
  const float* wk = (const float*)d_in[6];
  const float* bk = (const float*)d_in[7];
  const float* wv = (const float*)d_in[8];
  const float* bv = (const float*)d_in[9];
  const float* wo = (const float*)d_in[10];
  const float* bo = (const float*)d_in[11];

  float* xout = (float*)d_out;                       // [2,2048,1024]
  float* attn = xout + (size_t)2 * SEQ * DIM;        // [2,16,2048,2048]

  const size_t NBS = (size_t)2 * SEQ * DIM;          // 4,194,304
  const size_t NW = (size_t)DIM * DIM;               // 1,048,576

  __bf16* Qp = (__bf16*)d_ws;                        // bf16, pre-scaled 1/8
  __bf16* Kp = Qp + NBS;
  __bf16* Vt = Kp + NBS;                             // [32,64,2048] transposed V
  __bf16* Oc = Vt + NBS;                             // attention output, bf16
  __bf16* qb = Oc + NBS;                             // bf16 copies of inputs/weights
  __bf16* kb = qb + NBS;
  __bf16* vb = kb + NBS;
  __bf16* wqb = vb + NBS;
  __bf16* wkb = wqb + NW;
  __bf16* wvb = wkb + NW;
  __bf16* wob = wvb + NW;                            // total ws use: 64 MiB

  dim3 blk(256);

  dim3 g0(2048, 7);
  cvt_bf16<<<g0, blk, 0, stream>>>(q, k, v, wq, wk, wv, wo,
                                   qb, kb, vb, wqb, wkb, wvb, wob);

  dim3 g1(8, 32, 3);
  qkv_gemm<<<g1, blk, 0, stream>>>(qb, kb, vb, wqb, wkb, wvb, bq, bk, bv, Qp, Kp, Vt);

  dim3 g2(32, 32);
  attn_fused<<<g2, blk, 0, stream>>>(Qp, Kp, Vt, attn, Oc);

  dim3 g3(8, 32);
  out_gemm<<<g3, blk, 0, stream>>>(Oc, wob, bo, xout);
}

// Round 9
// 762.070 us; speedup vs baseline: 1.1075x; 1.1075x over previous
//
#include <hip/hip_runtime.h>
#include <hip/hip_bf16.h>

typedef __attribute__((ext_vector_type(8))) __bf16 bf16x8;
typedef __attribute__((ext_vector_type(4))) __bf16 bf16x4;
typedef __attribute__((ext_vector_type(4))) float f32x4;

#define MFMA16(a, b, c) __builtin_amdgcn_mfma_f32_16x16x32_bf16((a), (b), (c), 0, 0, 0)

// B=2, S=2048, D=1024, H=16, DK=64
#define SEQ 2048
#define DIM 1024

// Async global->LDS, 16B per lane. LDS dest must be WAVE-UNIFORM base
// (HW adds lane*16); global src is per-lane. LDS layout must be linear.
__device__ __forceinline__ void gload_lds16(const __bf16* g, __bf16* l) {
  __builtin_amdgcn_global_load_lds(
      (const __attribute__((address_space(1))) void*)g,
      (__attribute__((address_space(3))) void*)l, 16, 0, 0);
}

// ---------------------------------------------------------------------------
// One-shot fp32 -> bf16 convert of the 3 inputs and 4 weight matrices.
// RNE rounding via (__bf16) cast — numerics unchanged vs inline converts.
// ---------------------------------------------------------------------------
__global__ __launch_bounds__(256) void cvt_bf16(
    const float* __restrict__ q, const float* __restrict__ k, const float* __restrict__ v,
    const float* __restrict__ wq, const float* __restrict__ wk, const float* __restrict__ wv,
    const float* __restrict__ wo,
    __bf16* __restrict__ qb, __bf16* __restrict__ kb, __bf16* __restrict__ vb,
    __bf16* __restrict__ wqb, __bf16* __restrict__ wkb, __bf16* __restrict__ wvb,
    __bf16* __restrict__ wob) {
  int a = blockIdx.y;
  const float* src = (a == 0) ? q : (a == 1) ? k : (a == 2) ? v
                    : (a == 3) ? wq : (a == 4) ? wk : (a == 5) ? wv : wo;
  __bf16* dst = (a == 0) ? qb : (a == 1) ? kb : (a == 2) ? vb
               : (a == 3) ? wqb : (a == 4) ? wkb : (a == 5) ? wvb : wob;
  size_t n = (a < 3) ? (size_t)(2 * SEQ * DIM) : (size_t)(DIM * DIM);
  size_t i = ((size_t)blockIdx.x * 256 + threadIdx.x) * 8;
  if (i >= n) return;
  float4 f0 = *(const float4*)&src[i];
  float4 f1 = *(const float4*)&src[i + 4];
  bf16x8 o = {(__bf16)f0.x, (__bf16)f0.y, (__bf16)f0.z, (__bf16)f0.w,
              (__bf16)f1.x, (__bf16)f1.y, (__bf16)f1.z, (__bf16)f1.w};
  *(bf16x8*)&dst[i] = o;
}

// ---------------------------------------------------------------------------
// QKV projection, m97-style: double-buffered LINEAR LDS [2][128x32] staged via
// global_load_lds dwordx4 (no VGPR round-trip), ONE barrier per K-step — the
// pre-barrier vmcnt(0) drain completes the previous issue; next-tile loads fly
// under the current MFMAs.
// z==0 (Q): output pre-scaled by 0.125.  z==1 (K).  z==2 (V): stored
// TRANSPOSED as Vt[bh][dk][s].
// ---------------------------------------------------------------------------
__global__ __launch_bounds__(256) void qkv_gemm(
    const __bf16* __restrict__ qI, const __bf16* __restrict__ kI, const __bf16* __restrict__ vI,
    const __bf16* __restrict__ wqI, const __bf16* __restrict__ wkI, const __bf16* __restrict__ wvI,
    const float* __restrict__ bqI, const float* __restrict__ bkI, const float* __restrict__ bvI,
    __bf16* __restrict__ Qp, __bf16* __restrict__ Kp, __bf16* __restrict__ Vt) {
  const int N = 1024, K = 1024;
  int z = blockIdx.z;
  const __bf16* A = (z == 0) ? qI : (z == 1) ? kI : vI;
  const __bf16* W = (z == 0) ? wqI : (z == 1) ? wkI : wvI;
  const float* bias = (z == 0) ? bqI : (z == 1) ? bkI : bvI;

  __shared__ __bf16 As[2][128 * 32];   // linear, unpadded (global_load_lds req.)
  __shared__ __bf16 Bs[2][128 * 32];

  int tid = threadIdx.x;
  int wave = tid >> 6, lane = tid & 63;
  int quad = lane >> 4, l16 = lane & 15;
  int wm = (wave >> 1) * 64, wn = (wave & 1) * 64;
  int m0 = blockIdx.y * 128, n0 = blockIdx.x * 128;

  // staging geometry: lane covers row = wave*16 + lane/4 (+64 for 2nd issue),
  // col = (lane&3)*8.  Flat LDS elem = (wave*64+lane)*8 + issue*2048 — linear.
  int srow = wave * 16 + (lane >> 2);
  int scol = (lane & 3) * 8;
  const __bf16* Ab = &A[(size_t)(m0 + srow) * K + scol];
  const __bf16* Wb = &W[(size_t)(n0 + srow) * K + scol];
  int lo = wave * 512;                 // wave-uniform LDS element base

  f32x4 acc[4][4] = {};

  // prologue: stage tile 0 into buf 0
  {
    gload_lds16(Ab, &As[0][lo]);
    gload_lds16(Ab + (size_t)64 * K, &As[0][lo + 2048]);
    gload_lds16(Wb, &Bs[0][lo]);
    gload_lds16(Wb + (size_t)64 * K, &Bs[0][lo + 2048]);
  }

  int buf = 0;
  for (int k0 = 0; k0 < K; k0 += 32) {
    __syncthreads();                   // drains vmcnt(0): tile-k0 loads landed
    if (k0 + 32 < K) {
      int nb = buf ^ 1;
      gload_lds16(Ab + k0 + 32, &As[nb][lo]);
      gload_lds16(Ab + (size_t)64 * K + k0 + 32, &As[nb][lo + 2048]);
      gload_lds16(Wb + k0 + 32, &Bs[nb][lo]);
      gload_lds16(Wb + (size_t)64 * K + k0 + 32, &Bs[nb][lo + 2048]);
    }
    const __bf16* as = &As[buf][0];
    const __bf16* bs = &Bs[buf][0];
    bf16x8 af[4], bfv[4];
#pragma unroll
    for (int i = 0; i < 4; i++) af[i] = *(const bf16x8*)&as[(wm + i * 16 + l16) * 32 + quad * 8];
#pragma unroll
    for (int j = 0; j < 4; j++) bfv[j] = *(const bf16x8*)&bs[(wn + j * 16 + l16) * 32 + quad * 8];
#pragma unroll
    for (int i = 0; i < 4; i++)
#pragma unroll
      for (int j = 0; j < 4; j++) acc[i][j] = MFMA16(af[i], bfv[j], acc[i][j]);
    buf ^= 1;
  }

#pragma unroll
  for (int j = 0; j < 4; j++) {
    int col = n0 + wn + j * 16 + l16;
    float bj = bias[col];
    if (z == 2) {
      // transposed store: Vt[(bh*64+dk)*2048 + s], 4 consecutive s per lane
#pragma unroll
      for (int i = 0; i < 4; i++) {
        int row0 = m0 + wm + i * 16 + quad * 4;
        int bb = row0 >> 11, s = row0 & 2047;
        bf16x4 pv = {(__bf16)(acc[i][j][0] + bj), (__bf16)(acc[i][j][1] + bj),
                     (__bf16)(acc[i][j][2] + bj), (__bf16)(acc[i][j][3] + bj)};
        *(bf16x4*)&Vt[((size_t)bb * 1024 + col) * SEQ + s] = pv;
      }
    } else {
      __bf16* C = (z == 0) ? Qp : Kp;
      float scale = (z == 0) ? 0.125f : 1.0f;
#pragma unroll
      for (int i = 0; i < 4; i++)
#pragma unroll
        for (int r = 0; r < 4; r++) {
          int row = m0 + wm + i * 16 + quad * 4 + r;
          C[(size_t)row * N + col] = (__bf16)((acc[i][j][r] + bj) * scale);
        }
    }
  }
}

// ---------------------------------------------------------------------------
// Output projection, same m97-style structure. x[m,n] = sum_k Oc[m,k]*wo[n,k]
// + bo[n], fp32 out.
// ---------------------------------------------------------------------------
__global__ __launch_bounds__(256) void out_gemm(
    const __bf16* __restrict__ A, const __bf16* __restrict__ W,
    const float* __restrict__ bias, float* __restrict__ C) {
  const int N = 1024, K = 1024;
  __shared__ __bf16 As[2][128 * 32];
  __shared__ __bf16 Bs[2][128 * 32];

  int tid = threadIdx.x;
  int wave = tid >> 6, lane = tid & 63;
  int quad = lane >> 4, l16 = lane & 15;
  int wm = (wave >> 1) * 64, wn = (wave & 1) * 64;
  int m0 = blockIdx.y * 128, n0 = blockIdx.x * 128;

  int srow = wave * 16 + (lane >> 2);
  int scol = (lane & 3) * 8;
  const __bf16* Ab = &A[(size_t)(m0 + srow) * K + scol];
  const __bf16* Wb = &W[(size_t)(n0 + srow) * K + scol];
  int lo = wave * 512;

  f32x4 acc[4][4] = {};

  {
    gload_lds16(Ab, &As[0][lo]);
    gload_lds16(Ab + (size_t)64 * K, &As[0][lo + 2048]);
    gload_lds16(Wb, &Bs[0][lo]);
    gload_lds16(Wb + (size_t)64 * K, &Bs[0][lo + 2048]);
  }

  int buf = 0;
  for (int k0 = 0; k0 < K; k0 += 32) {
    __syncthreads();
    if (k0 + 32 < K) {
      int nb = buf ^ 1;
      gload_lds16(Ab + k0 + 32, &As[nb][lo]);
      gload_lds16(Ab + (size_t)64 * K + k0 + 32, &As[nb][lo + 2048]);
      gload_lds16(Wb + k0 + 32, &Bs[nb][lo]);
      gload_lds16(Wb + (size_t)64 * K + k0 + 32, &Bs[nb][lo + 2048]);
    }
    const __bf16* as = &As[buf][0];
    const __bf16* bs = &Bs[buf][0];
    bf16x8 af[4], bfv[4];
#pragma unroll
    for (int i = 0; i < 4; i++) af[i] = *(const bf16x8*)&as[(wm + i * 16 + l16) * 32 + quad * 8];
#pragma unroll
    for (int j = 0; j < 4; j++) bfv[j] = *(const bf16x8*)&bs[(wn + j * 16 + l16) * 32 + quad * 8];
#pragma unroll
    for (int i = 0; i < 4; i++)
#pragma unroll
      for (int j = 0; j < 4; j++) acc[i][j] = MFMA16(af[i], bfv[j], acc[i][j]);
    buf ^= 1;
  }

#pragma unroll
  for (int j = 0; j < 4; j++) {
    int col = n0 + wn + j * 16 + l16;
    float bj = bias[col];
#pragma unroll
    for (int i = 0; i < 4; i++)
#pragma unroll
      for (int r = 0; r < 4; r++) {
        int row = m0 + wm + i * 16 + quad * 4 + r;
        C[(size_t)row * N + col] = acc[i][j][r] + bj;
      }
  }
}

// ---------------------------------------------------------------------------
// Fused causal attention, S^T orientation, LDS-staged K/V (proven 763.8 µs
// config — session best). Q fragments load directly from global (read once);
// padded LDS strides give conflict-free-per-phase b128 access (the bank
// distribution 4*(l16+quad) mod 32 = 8 groups x 8 lanes = structural optimum
// for wave-wide b128; verified by R8's swizzle experiment regressing +80 µs).
//
// C-layout of S^T = K·Q^T per lane (quad,l16): q = l16, k = t*16 + quad*4+r
// => float4 attn stores, bf16x4 Ps writes, softmax row-reduce is
// shfl_xor(16)+shfl_xor(32). V pre-transposed (Vt[bh][dk][s]) => vectorized
// staging, no LDS transpose. Q pre-scaled by 1/8 in the projection.
// Block = 256 threads (4 waves); wave w owns q rows q0+16w .. q0+16w+15.
// LDS: Ks 18.4 + Vts 17.4 + Ps 17.4 = 53 KB.
// ---------------------------------------------------------------------------
__global__ __launch_bounds__(256) void attn_fused(
    const __bf16* __restrict__ Qp, const __bf16* __restrict__ Kp,
    const __bf16* __restrict__ Vt, float* __restrict__ attn,
    __bf16* __restrict__ Oc) {
  int bh = blockIdx.y;
  int b = bh >> 4;
  int hofs = (bh & 15) * 64;
  int q0 = blockIdx.x * 64;

  int tid = threadIdx.x;
  int wave = tid >> 6, lane = tid & 63;
  int quad = lane >> 4, l16 = lane & 15;

  __shared__ __bf16 Ks[128][72];    // 144 B row stride
  __shared__ __bf16 Vts[64][136];   // V^T tile [dk][k], staged directly
  __shared__ __bf16 Ps[64][136];    // P tile [q][k] bf16

  const size_t rowbase = (size_t)b * SEQ;
  const size_t vtbase = (size_t)bh * 64 * SEQ;

  int qg = q0 + wave * 16 + l16;   // this lane's q row

  // loop-invariant Q B-fragments straight from global (one-time, latency
  // amortized over the whole kernel)
  const __bf16* qpp = &Qp[(rowbase + qg) * DIM + hofs + quad * 8];
  bf16x8 qfrag0 = *(const bf16x8*)qpp;
  bf16x8 qfrag1 = *(const bf16x8*)(qpp + 32);

  float m_i = -1e30f, l_i = 0.f;
  int ktmax = (q0 + 63) >> 7;

  // ---------------- pass 1: row stats ----------------
  for (int kt = 0; kt <= ktmax; kt++) {
    int k0 = kt << 7;
    __syncthreads();
#pragma unroll
    for (int it = 0; it < 4; it++) {
      int flat = tid * 8 + it * 2048;
      int r = flat >> 6, c = flat & 63;
      *(bf16x8*)&Ks[r][c] = *(const bf16x8*)&Kp[(rowbase + k0 + r) * DIM + hofs + c];
    }
    __syncthreads();

    f32x4 sacc[8] = {};
#pragma unroll
    for (int t = 0; t < 8; t++) {
      bf16x8 a0 = *(bf16x8*)&Ks[t * 16 + l16][quad * 8];
      bf16x8 a1 = *(bf16x8*)&Ks[t * 16 + l16][32 + quad * 8];
      sacc[t] = MFMA16(a0, qfrag0, sacc[t]);
      sacc[t] = MFMA16(a1, qfrag1, sacc[t]);
    }

    bool diag = (kt == ktmax);
    float sv[32];
    float mx = -1e30f;
#pragma unroll
    for (int t = 0; t < 8; t++)
#pragma unroll
      for (int r = 0; r < 4; r++) {
        float s = sacc[t][r];
        int k = k0 + t * 16 + quad * 4 + r;
        if (diag && k > qg) s = -1e30f;
        sv[t * 4 + r] = s;
        mx = fmaxf(mx, s);
      }
    mx = fmaxf(mx, __shfl_xor(mx, 16));
    mx = fmaxf(mx, __shfl_xor(mx, 32));
    float mn = fmaxf(m_i, mx);
    float sum = 0.f;
#pragma unroll
    for (int i = 0; i < 32; i++) sum += __expf(sv[i] - mn);
    sum += __shfl_xor(sum, 16);
    sum += __shfl_xor(sum, 32);
    l_i = l_i * __expf(m_i - mn) + sum;
    m_i = mn;
  }

  float rl = 1.f / l_i;
  f32x4 oacc[4] = {};
  float* attn_bh = attn + (size_t)bh * SEQ * SEQ;
  float* attn_row = attn_bh + (size_t)qg * SEQ;

  // ---------------- pass 2: P write + O accumulate ----------------
  for (int kt = 0; kt < SEQ / 128; kt++) {
    int k0 = kt << 7;
    if (kt <= ktmax) {
      __syncthreads();
#pragma unroll
      for (int it = 0; it < 4; it++) {
        int flat = tid * 8 + it * 2048;
        int r = flat >> 6, c = flat & 63;
        *(bf16x8*)&Ks[r][c] = *(const bf16x8*)&Kp[(rowbase + k0 + r) * DIM + hofs + c];
        int d = flat >> 7, c2 = flat & 127;
        *(bf16x8*)&Vts[d][c2] = *(const bf16x8*)&Vt[vtbase + (size_t)d * SEQ + k0 + c2];
      }
      __syncthreads();

      f32x4 sacc[8] = {};
#pragma unroll
      for (int t = 0; t < 8; t++) {
        bf16x8 a0 = *(bf16x8*)&Ks[t * 16 + l16][quad * 8];
        bf16x8 a1 = *(bf16x8*)&Ks[t * 16 + l16][32 + quad * 8];
        sacc[t] = MFMA16(a0, qfrag0, sacc[t]);
        sacc[t] = MFMA16(a1, qfrag1, sacc[t]);
      }

      bool diag = (kt == ktmax);
#pragma unroll
      for (int t = 0; t < 8; t++) {
        float p[4];
#pragma unroll
        for (int r = 0; r < 4; r++) {
          int k = k0 + t * 16 + quad * 4 + r;
          float s = sacc[t][r];
          p[r] = (!diag || k <= qg) ? __expf(s - m_i) * rl : 0.f;
        }
        *(float4*)&attn_row[k0 + t * 16 + quad * 4] = make_float4(p[0], p[1], p[2], p[3]);
        bf16x4 ph = {(__bf16)p[0], (__bf16)p[1], (__bf16)p[2], (__bf16)p[3]};
        *(bf16x4*)&Ps[wave * 16 + l16][t * 16 + quad * 4] = ph;
      }
      __syncthreads();   // Ps cross-lane visibility

#pragma unroll
      for (int ks = 0; ks < 4; ks++) {
        bf16x8 a = *(bf16x8*)&Ps[wave * 16 + l16][ks * 32 + quad * 8];
#pragma unroll
        for (int dt = 0; dt < 4; dt++) {
          bf16x8 bb = *(bf16x8*)&Vts[dt * 16 + l16][ks * 32 + quad * 8];
          oacc[dt] = MFMA16(a, bb, oacc[dt]);
        }
      }
    } else {
      // fully-masked tile: write exact zeros
      float4 z4 = make_float4(0.f, 0.f, 0.f, 0.f);
#pragma unroll
      for (int i = 0; i < 8; i++) {
        int f4 = tid + i * 256;
        int r = f4 >> 5;
        int c = (f4 & 31) * 4;
        *(float4*)&attn_bh[(size_t)(q0 + r) * SEQ + k0 + c] = z4;
      }
    }
  }

  // write O strip (bf16): C-layout col=l16=dk, row=quad*4+rr=q-within-wave
#pragma unroll
  for (int dt = 0; dt < 4; dt++)
#pragma unroll
    for (int rr = 0; rr < 4; rr++) {
      int row = q0 + wave * 16 + quad * 4 + rr;
      Oc[(rowbase + row) * DIM + hofs + dt * 16 + l16] = (__bf16)oacc[dt][rr];
    }
}

// ---------------------------------------------------------------------------
extern "C" void kernel_launch(void* const* d_in, const int* in_sizes, int n_in,
                              void* d_out, int out_size, void* d_ws, size_t ws_size,
                              hipStream_t stream) {
  const float* q = (const float*)d_in[0];
  const float* k = (const float*)d_in[1];
  const float* v = (const float*)d_in[2];
  // d_in[3] = causal mask (tril) — analytic in attn_fused
  const float* wq = (const float*)d_in[4];
  const float* bq = (const float*)d_in[5];
  const float* wk = (const float*)d_in[6];
  const float* bk = (const float*)d_in[7];
  const float* wv = (const float*)d_in[8];
  const float* bv = (const float*)d_in[9];
  const float* wo = (const float*)d_in[10];
  const float* bo = (const float*)d_in[11];

  float* xout = (float*)d_out;                       // [2,2048,1024]
  float* attn = xout + (size_t)2 * SEQ * DIM;        // [2,16,2048,2048]

  const size_t NBS = (size_t)2 * SEQ * DIM;          // 4,194,304
  const size_t NW = (size_t)DIM * DIM;               // 1,048,576

  __bf16* Qp = (__bf16*)d_ws;                        // bf16, pre-scaled 1/8
  __bf16* Kp = Qp + NBS;
  __bf16* Vt = Kp + NBS;                             // [32,64,2048] transposed V
  __bf16* Oc = Vt + NBS;                             // attention output, bf16
  __bf16* qb = Oc + NBS;                             // bf16 copies of inputs/weights
  __bf16* kb = qb + NBS;
  __bf16* vb = kb + NBS;
  __bf16* wqb = vb + NBS;
  __bf16* wkb = wqb + NW;
  __bf16* wvb = wkb + NW;
  __bf16* wob = wvb + NW;                            // total ws use: 64 MiB

  dim3 blk(256);

  dim3 g0(2048, 7);
  cvt_bf16<<<g0, blk, 0, stream>>>(q, k, v, wq, wk, wv, wo,
                                   qb, kb, vb, wqb, wkb, wvb, wob);

  dim3 g1(8, 32, 3);
  qkv_gemm<<<g1, blk, 0, stream>>>(qb, kb, vb, wqb, wkb, wvb, bq, bk, bv, Qp, Kp, Vt);

  dim3 g2(32, 32);
  attn_fused<<<g2, blk, 0, stream>>>(Qp, Kp, Vt, attn, Oc);

  dim3 g3(8, 32);
  out_gemm<<<g3, blk, 0, stream>>>(Oc, wob, bo, xout);
}